// Round 11
// baseline (338.241 us; speedup 1.0000x reference)
//
#include <hip/hip_runtime.h>
#include <hip/hip_bf16.h>
#include <stdint.h>

#define VOCAB 50000
#define EMB   300
#define EMBP  320   // K padded to multiple of 64
#define HID   128
#define NGATE 512   // 4*HID
#define BATCH 1024
#define SEQ   200
#define ROWS  4     // batch rows per k_lstm block (256 blocks, 1/CU)
#define L2E   1.4426950408889634f

typedef __attribute__((ext_vector_type(8))) short short8;
typedef __attribute__((ext_vector_type(4))) float f32x4;

#define AS1 __attribute__((address_space(1)))
#define AS3 __attribute__((address_space(3)))

static __device__ __forceinline__ void gload_lds16(const void* g, void* s) {
  __builtin_amdgcn_global_load_lds((const AS1 uint32_t*)g, (AS3 uint32_t*)s, 16, 0, 0);
}

static __device__ __forceinline__ unsigned short f2bf(float f) {
  union { float f; unsigned u; } v; v.f = f;
  unsigned r = v.u + 0x7fffu + ((v.u >> 16) & 1u);
  return (unsigned short)(r >> 16);
}
static __device__ __forceinline__ float blo2f(unsigned u) {
  union { unsigned u; float f; } v; v.u = u << 16; return v.f;
}
static __device__ __forceinline__ float bhi2f(unsigned u) {
  union { unsigned u; float f; } v; v.u = u & 0xffff0000u; return v.f;
}
static __device__ __forceinline__ float sigmf(float x) {
  return __fdividef(1.0f, 1.0f + __expf(-x));
}
// z pre-scaled by log2(e): sigmoid(a) = 1/(1+2^-z)
static __device__ __forceinline__ float sig2(float z) {
  return __builtin_amdgcn_rcpf(1.0f + __builtin_amdgcn_exp2f(-z));
}

// ---------------- prep: f32 -> bf16 (K-pad; optional perm / gate scale) ----
__global__ void k_cvt_pad(const float* __restrict__ src, unsigned short* __restrict__ dst,
                          int rows, int sc, int dc, int perm, int smode) {
  int idx = blockIdx.x * blockDim.x + threadIdx.x;
  int cpr = dc >> 3;
  if (idx >= rows * cpr) return;
  int row = idx / cpr, k0 = (idx - row * cpr) * 8;
  float s = 1.0f;
  if (smode) s = ((row >> 7) == 2) ? (2.0f * L2E) : L2E;
  uint4 pack;
  unsigned short* v = (unsigned short*)&pack;
#pragma unroll
  for (int j = 0; j < 8; j++) {
    int k = k0 + j;
    v[j] = (k < sc) ? f2bf(src[(long)row * sc + k] * s) : (unsigned short)0;
  }
  int drow = perm ? ((row & 127) * 4 + (row >> 7)) : row;
  *(uint4*)(dst + (long)drow * dc + k0) = pack;
}

// permuted+scaled bias: o[hid*4+g] = (a[g*128+hid]+b[...]) * s_g
__global__ void k_bias(const float* __restrict__ a, const float* __restrict__ b,
                       float* __restrict__ o) {
  int i = blockIdx.x * blockDim.x + threadIdx.x;
  if (i < NGATE) {
    int g = i >> 7, hid = i & 127;
    float s = (g == 2) ? (2.0f * L2E) : L2E;
    o[hid * 4 + g] = (a[i] + b[i]) * s;
  }
}

// ---------------- kernel 1: gathered GEMM, SINGLE-SHOT A panel -------------
// 1600 blocks x 512 threads. Block = one M-tile (128 gathered emb rows) x
// FULL N=512. A panel (128x640B = 80KB) staged in ONE burst -> one L3
// latency exposure per block (was five). A-frags hoisted to registers (80
// VGPR) and reused across all 4 n-tiles. B streams via 2x16KB double
// buffer (L2-hot). LDS 112KB, 1 block/CU.
__global__ __launch_bounds__(512, 1) void k_xg_gemm(
    const int* __restrict__ x, const unsigned short* __restrict__ embb,
    const unsigned short* __restrict__ wihb, const float* __restrict__ biasp,
    unsigned short* __restrict__ xg) {
  __shared__ __align__(16) unsigned short Al[128 * EMBP];     // 81,920 B
  __shared__ __align__(16) unsigned short Bl[2][128 * 64];    // 32,768 B
  const int tid = threadIdx.x;
  const int lane = tid & 63;
  const int tile_m = blockIdx.x;            // 0..1599
  const int t_idx = tile_m >> 3;
  const int b0 = (tile_m & 7) * 128;

  // ---- stage A panel: 10 chunks/thread, c = tid + i*512 -> (r = c/40, s = c%40)
  // LDS dst linear (phys slot s); source slot sigma = s ^ (r&7)
#pragma unroll
  for (int i = 0; i < 10; i++) {
    const unsigned c = tid + i * 512;
    const unsigned r = c / 40u;
    const unsigned s = c - r * 40u;
    const unsigned sg = s ^ (r & 7u);
    const long ridx = x[(b0 + r) * SEQ + t_idx];
    gload_lds16(embb + ridx * EMBP + sg * 8, (char*)Al + c * 16);
  }
  // ---- stage B chunk 0 (n=0, ckt=0) into buf 0: 2 chunks/thread
  const unsigned bc0 = tid;            // c = tid + i*512, i<2
  const unsigned br0 = bc0 >> 3, bp0 = bc0 & 7;
  const unsigned bs0 = bp0 ^ (br0 & 7);
  const unsigned bc1 = tid + 512;
  const unsigned br1 = bc1 >> 3, bp1 = bc1 & 7;
  const unsigned bs1 = bp1 ^ (br1 & 7);
  gload_lds16(wihb + (long)br0 * EMBP + 0 * 64 + bs0 * 8, (char*)Bl + bc0 * 16);
  gload_lds16(wihb + (long)br1 * EMBP + 0 * 64 + bs1 * 8, (char*)Bl + bc1 * 16);
  __syncthreads();

  // ---- wave mapping: 8 waves = 4 wrow (32 M-rows) x 2 wcol (64 N-cols)
  const int wid = tid >> 6;
  const int wrow = wid >> 1, wcol = wid & 1;
  const int l15 = lane & 15, lgrp = lane >> 4;
  const int swz7 = l15 & 7;

  // ---- A fragments: af[mt][kt], rows wrow*32+mt*16+l15, held all kernel
  short8 af[2][10];
#pragma unroll
  for (int mt = 0; mt < 2; mt++) {
    const int arow = wrow * 32 + mt * 16 + l15;
    const char* abase = (const char*)Al + arow * (EMBP * 2);
#pragma unroll
    for (int kt = 0; kt < 10; kt++)
      af[mt][kt] = *(const short8*)(abase + (((kt * 4 + lgrp) ^ swz7) << 4));
  }

  f32x4 acc[2][4];
  const int brow_frag = wcol * 64;     // base N-row of this wave's B frags

#pragma unroll
  for (int n = 0; n < 4; n++) {
    const int n0 = n * 128;
    float bv[4];
#pragma unroll
    for (int nt = 0; nt < 4; nt++) bv[nt] = biasp[n0 + brow_frag + nt * 16 + l15];
#pragma unroll
    for (int mt = 0; mt < 2; mt++)
#pragma unroll
      for (int nt = 0; nt < 4; nt++) acc[mt][nt] = (f32x4){0.f, 0.f, 0.f, 0.f};

#pragma unroll
    for (int ckt = 0; ckt < 5; ckt++) {
      const int cc = n * 5 + ckt;
      // stage next B chunk (cc+1) into buf (cc+1)&1
      if (cc < 19) {
        const int n2 = (cc + 1) / 5, k2 = (cc + 1) % 5;
        char* bbuf = (char*)Bl + ((cc + 1) & 1) * 16384;
        gload_lds16(wihb + (long)(n2 * 128 + br0) * EMBP + k2 * 64 + bs0 * 8, bbuf + bc0 * 16);
        gload_lds16(wihb + (long)(n2 * 128 + br1) * EMBP + k2 * 64 + bs1 * 8, bbuf + bc1 * 16);
      }
      // B fragments from buf cc&1
      const char* bbase = (const char*)Bl + (cc & 1) * 16384;
      short8 bf[4][2];
#pragma unroll
      for (int nt = 0; nt < 4; nt++) {
        const int brow = brow_frag + nt * 16 + l15;
        const char* bb = bbase + brow * 128;
#pragma unroll
        for (int kk = 0; kk < 2; kk++)
          bf[nt][kk] = *(const short8*)(bb + (((kk * 4 + lgrp) ^ swz7) << 4));
      }
#pragma unroll
      for (int kk = 0; kk < 2; kk++)
#pragma unroll
        for (int mt = 0; mt < 2; mt++)
#pragma unroll
          for (int nt = 0; nt < 4; nt++)
            acc[mt][nt] = __builtin_amdgcn_mfma_f32_16x16x32_bf16(
                af[mt][ckt * 2 + kk], bf[nt][kk], acc[mt][nt], 0, 0, 0);
      __syncthreads();
    }

    // epilogue for this n-tile (global stores only, no LDS)
#pragma unroll
    for (int mt = 0; mt < 2; mt++)
#pragma unroll
      for (int nt = 0; nt < 4; nt++) {
        const int colg = n0 + brow_frag + nt * 16 + l15;
#pragma unroll
        for (int j = 0; j < 4; j++) {
          const long m = (long)tile_m * 128 + wrow * 32 + mt * 16 + lgrp * 4 + j;
          xg[m * NGATE + colg] = f2bf(acc[mt][nt][j] + bv[nt]);
        }
      }
  }
}

// ---------------- kernel 2: sequential LSTM (R9 champion, verbatim) --------
__global__ __launch_bounds__(512, 2) void k_lstm(
    const unsigned short* __restrict__ xg, const unsigned short* __restrict__ whhp,
    float* __restrict__ hfin) {
  __shared__ __align__(16) unsigned short h_lds[2 * 4 * 128];  // 2KB dbuf, XOR-swizzled
  __shared__ __align__(16) float scratch[8 * 256];             // 8KB: 1KB per wave
  const int tid = threadIdx.x;
  const int lane = tid & 63;
  const int wid = tid >> 6;        // hidden block (16 hids)
  const int b0 = blockIdx.x * ROWS;
  const int l15 = lane & 15;
  const int lgrp = lane >> 4;      // 0..3
  const int hid = wid * 16 + l15;  // updater's hid

  // A-operand: permuted w_hh rows n' = wid*64 + nt*16 + l15, k = kt*32+lgrp*8
  short8 wfr[4][4];
#pragma unroll
  for (int nt = 0; nt < 4; nt++)
#pragma unroll
    for (int kt = 0; kt < 4; kt++)
      wfr[nt][kt] = *(const short8*)(whhp + (long)(wid * 64 + nt * 16 + l15) * HID + kt * 32 + lgrp * 8);

  float c_r = 0.0f, h_r = 0.0f;    // element (row=lgrp, hid)

  ((unsigned*)h_lds)[tid] = 0;     // 512 x 4B = 2KB (both parities)
  __syncthreads();

  // B-frag (h^T): lane l15 -> batch row l15&3 (rows 4-15 dup -> garbage cols)
  const int ar = l15 & 3;
  int rdoff[4];
#pragma unroll
  for (int kt = 0; kt < 4; kt++)
    rdoff[kt] = ar * 256 + ((kt * 64 + lgrp * 16) ^ (ar << 5));
  const int hwoff = lgrp * 256 + ((2 * hid) ^ (lgrp << 5));
  const char* lb = (const char*)h_lds;

  // wave-private scratch: float addr (row r)*64 + ((hidloc*4) ^ (r*4))
  float* sw = scratch + wid * 256;
  int swr[4];                       // write: r=l15 (<4), hidloc = nt*4+lgrp
#pragma unroll
  for (int nt = 0; nt < 4; nt++)
    swr[nt] = l15 * 64 + (((nt * 4 + lgrp) * 4) ^ (l15 * 4));
  const int srd = lgrp * 64 + ((l15 * 4) ^ (lgrp * 4));  // read: r=lgrp, hidloc=l15

  // xg: elem ((t*BATCH + row)*HID + hid)*4 + gate ; this lane: row=lgrp
  const unsigned short* xbase = xg + ((long)(b0 + lgrp) * HID + hid) * 4;
  const long TSTEP = (long)BATCH * HID * 4;
  uint2 xA = *(const uint2*)xbase;
  uint2 xB = *(const uint2*)(xbase + TSTEP);
  const unsigned short* xnext = xbase + 2 * TSTEP;

#define STEP_BODY(XS, RB, WB, T)                                               \
  {                                                                            \
    const float xf0 = blo2f(XS.x), xf1 = bhi2f(XS.x);                          \
    const float xf2 = blo2f(XS.y), xf3 = bhi2f(XS.y);                          \
    if ((T) + 2 < SEQ) XS = *(const uint2*)xnext;                              \
    short8 hf[4];                                                              \
    _Pragma("unroll") for (int kt = 0; kt < 4; kt++)                           \
      hf[kt] = *(const short8*)(lb + (RB) + rdoff[kt]);                        \
    f32x4 acc[4];                                                              \
    _Pragma("unroll") for (int nt = 0; nt < 4; nt++)                           \
      acc[nt] = (f32x4){0.f, 0.f, 0.f, 0.f};                                   \
    _Pragma("unroll") for (int kt = 0; kt < 4; kt++)                           \
      _Pragma("unroll") for (int nt = 0; nt < 4; nt++)                         \
        acc[nt] = __builtin_amdgcn_mfma_f32_16x16x32_bf16(wfr[nt][kt], hf[kt], \
                                                          acc[nt], 0, 0, 0);   \
    if (l15 < 4) {                                                             \
      _Pragma("unroll") for (int nt = 0; nt < 4; nt++)                         \
        *(f32x4*)(sw + swr[nt]) = acc[nt];                                     \
    }                                                                          \
    __builtin_amdgcn_sched_barrier(0);                                         \
    const f32x4 g4 = *(const f32x4*)(sw + srd);                                \
    const float zi = g4[0] + xf0;                                              \
    const float zf = g4[1] + xf1;                                              \
    const float zg = g4[2] + xf2;                                              \
    const float zo = g4[3] + xf3;                                              \
    const float iv = sig2(zi);                                                 \
    const float fv = sig2(zf);                                                 \
    const float gv = 2.0f * sig2(zg) - 1.0f;                                   \
    const float ov = sig2(zo);                                                 \
    c_r = fv * c_r + iv * gv;                                                  \
    const float tc = 2.0f * sig2(c_r * (2.0f * L2E)) - 1.0f;                   \
    h_r = ov * tc;                                                             \
    *(unsigned short*)((char*)h_lds + (WB) + hwoff) = f2bf(h_r);               \
    asm volatile("s_waitcnt lgkmcnt(0)" ::: "memory");                         \
    __builtin_amdgcn_s_barrier();                                              \
    __builtin_amdgcn_sched_barrier(0);                                         \
  }

  for (int t = 0; t < SEQ; t += 2) {
    STEP_BODY(xA, 0, 1024, t);
    xnext += TSTEP;
    STEP_BODY(xB, 1024, 0, t + 1);
    xnext += TSTEP;
  }
#undef STEP_BODY

  hfin[(b0 + lgrp) * HID + hid] = h_r;
}

// ---------------- kernel 3: FC head, one wave per batch row ----------------
__global__ void k_head(const float* __restrict__ hfin,
                       const float* __restrict__ fc1w, const float* __restrict__ fc1b,
                       const float* __restrict__ fc2w, const float* __restrict__ fc2b,
                       float* __restrict__ out) {
  const int tid = threadIdx.x;
  const int lane = tid & 63;
  const int wid = tid >> 6;
  const int row = blockIdx.x * 4 + wid;
  const float* h = hfin + row * HID;
  const float* w = fc1w + lane * HID;
  float acc = 0.0f;
#pragma unroll
  for (int k = 0; k < HID; k += 4) {
    const f32x4 hv = *(const f32x4*)(h + k);
    const f32x4 wv = *(const f32x4*)(w + k);
    acc += hv[0] * wv[0] + hv[1] * wv[1] + hv[2] * wv[2] + hv[3] * wv[3];
  }
  const float h1 = fmaxf(acc + fc1b[lane], 0.0f);
  float v = h1 * fc2w[lane];
#pragma unroll
  for (int off = 32; off > 0; off >>= 1) v += __shfl_down(v, off, 64);
  if (lane == 0) out[row] = sigmf(v + fc2b[0]);
}

// ---------------------------------------------------------------------------
extern "C" void kernel_launch(void* const* d_in, const int* in_sizes, int n_in,
                              void* d_out, int out_size, void* d_ws, size_t ws_size,
                              hipStream_t stream) {
  const int*   x    = (const int*)d_in[0];
  const float* emb  = (const float*)d_in[1];
  const float* w_ih = (const float*)d_in[2];
  const float* w_hh = (const float*)d_in[3];
  const float* b_ih = (const float*)d_in[4];
  const float* b_hh = (const float*)d_in[5];
  const float* fc1w = (const float*)d_in[6];
  const float* fc1b = (const float*)d_in[7];
  const float* fc2w = (const float*)d_in[8];
  const float* fc2b = (const float*)d_in[9];
  float* out = (float*)d_out;
  char* ws = (char*)d_ws;

  unsigned short* embb = (unsigned short*)(ws + 0);            // 32,000,000
  unsigned short* wihb = (unsigned short*)(ws + 32000000);     //    327,680
  unsigned short* whhp = (unsigned short*)(ws + 32327680);     //    131,072 (PERMUTED w_hh)
  float*          biasp= (float*)(ws + 32458752);              //      2,048
  float*          hfinp= (float*)(ws + 32460800);              //    524,288
  unsigned short* xgb  = (unsigned short*)(ws + 32985088);     // 209,715,200

  k_cvt_pad<<<dim3((VOCAB * (EMBP / 8) + 255) / 256), dim3(256), 0, stream>>>(emb, embb, VOCAB, EMB, EMBP, 0, 0);
  k_cvt_pad<<<dim3((NGATE * (EMBP / 8) + 255) / 256), dim3(256), 0, stream>>>(w_ih, wihb, NGATE, EMB, EMBP, 1, 1);
  k_cvt_pad<<<dim3((NGATE * (HID / 8) + 255) / 256), dim3(256), 0, stream>>>(w_hh, whhp, NGATE, HID, HID, 1, 1);
  k_bias<<<dim3(2), dim3(256), 0, stream>>>(b_ih, b_hh, biasp);
  k_xg_gemm<<<dim3(1600), dim3(512), 0, stream>>>(x, embb, wihb, biasp, xgb);
  k_lstm<<<dim3(BATCH / ROWS), dim3(512), 0, stream>>>(xgb, whhp, hfinp);
  k_head<<<dim3(256), dim3(256), 0, stream>>>(hfinp, fc1w, fc1b, fc2w, fc2b, out);
  (void)in_sizes; (void)n_in; (void)out_size; (void)ws_size;
}

// Round 12
// 282.877 us; speedup vs baseline: 1.1957x; 1.1957x over previous
//
#include <hip/hip_runtime.h>
#include <hip/hip_bf16.h>
#include <stdint.h>

#define VOCAB 50000
#define EMB   300
#define EMBP  320   // K padded to multiple of 64
#define HID   128
#define NGATE 512   // 4*HID
#define BATCH 1024
#define SEQ   200
#define ROWS  4     // batch rows per k_lstm block (256 blocks, 1/CU)
#define L2E   1.4426950408889634f

typedef __attribute__((ext_vector_type(8))) short short8;
typedef __attribute__((ext_vector_type(4))) float f32x4;

#define AS1 __attribute__((address_space(1)))
#define AS3 __attribute__((address_space(3)))

static __device__ __forceinline__ void gload_lds16(const void* g, void* s) {
  __builtin_amdgcn_global_load_lds((const AS1 uint32_t*)g, (AS3 uint32_t*)s, 16, 0, 0);
}

static __device__ __forceinline__ unsigned short f2bf(float f) {
  union { float f; unsigned u; } v; v.f = f;
  unsigned r = v.u + 0x7fffu + ((v.u >> 16) & 1u);
  return (unsigned short)(r >> 16);
}
static __device__ __forceinline__ float blo2f(unsigned u) {
  union { unsigned u; float f; } v; v.u = u << 16; return v.f;
}
static __device__ __forceinline__ float bhi2f(unsigned u) {
  union { unsigned u; float f; } v; v.u = u & 0xffff0000u; return v.f;
}
static __device__ __forceinline__ float sigmf(float x) {
  return __fdividef(1.0f, 1.0f + __expf(-x));
}
// z pre-scaled by log2(e): sigmoid(a) = 1/(1+2^-z)
static __device__ __forceinline__ float sig2(float z) {
  return __builtin_amdgcn_rcpf(1.0f + __builtin_amdgcn_exp2f(-z));
}

// ---------------- prep: f32 -> bf16 (K-pad; optional perm / gate scale) ----
__global__ void k_cvt_pad(const float* __restrict__ src, unsigned short* __restrict__ dst,
                          int rows, int sc, int dc, int perm, int smode) {
  int idx = blockIdx.x * blockDim.x + threadIdx.x;
  int cpr = dc >> 3;
  if (idx >= rows * cpr) return;
  int row = idx / cpr, k0 = (idx - row * cpr) * 8;
  float s = 1.0f;
  if (smode) s = ((row >> 7) == 2) ? (2.0f * L2E) : L2E;
  uint4 pack;
  unsigned short* v = (unsigned short*)&pack;
#pragma unroll
  for (int j = 0; j < 8; j++) {
    int k = k0 + j;
    v[j] = (k < sc) ? f2bf(src[(long)row * sc + k] * s) : (unsigned short)0;
  }
  int drow = perm ? ((row & 127) * 4 + (row >> 7)) : row;
  *(uint4*)(dst + (long)drow * dc + k0) = pack;
}

// permuted+scaled bias: o[hid*4+g] = (a[g*128+hid]+b[...]) * s_g
__global__ void k_bias(const float* __restrict__ a, const float* __restrict__ b,
                       float* __restrict__ o) {
  int i = blockIdx.x * blockDim.x + threadIdx.x;
  if (i < NGATE) {
    int g = i >> 7, hid = i & 127;
    float s = (g == 2) ? (2.0f * L2E) : L2E;
    o[hid * 4 + g] = (a[i] + b[i]) * s;
  }
}

// ---------------- kernel 1: gathered GEMM  xg = emb[x] @ w_ih_perm^T + bias
// R8 structure (128x128 tile, 2-phase dbuf, XCD co-location, 64KB LDS,
// 2 blocks/CU) but with 512 threads / 8 WAVES per block (wave = 32x64
// output, acc 2x4, 80 MFMA/wave): 4 waves/SIMD (2x R8's TLP) to hide the
// gather/barrier latency that left R8/R11 ~85% stalled. Scalar epilogue
// (R11 counters proved no write amplification). Bitwise-identical math.
__global__ __launch_bounds__(512, 4) void k_xg_gemm(
    const int* __restrict__ x, const unsigned short* __restrict__ embb,
    const unsigned short* __restrict__ wihb, const float* __restrict__ biasp,
    unsigned short* __restrict__ xg) {
  __shared__ __align__(16) unsigned short Al[2][128 * 64];   // 32 KB
  __shared__ __align__(16) unsigned short Bl[2][128 * 64];   // 32 KB
  const int tid = threadIdx.x;
  const int lane = tid & 63;
  // XCD co-location: bid = q*8 + xcd ; tile_m = xcd*200 + q/4 ; tile_n = q%4
  const int bid = blockIdx.x;
  const int xcd = bid & 7;
  const int q = bid >> 3;                   // 0..799
  const int tile_m = xcd * 200 + (q >> 2);  // 0..1599
  const int tile_n = q & 3;
  const int t_idx = tile_m >> 3;            // 1024 % 128 == 0 -> tile same t
  const int b0 = (tile_m & 7) * 128;
  const int n0 = tile_n * 128;

  // staging: chunk c = tid + i*512 (i<2); row = c>>3, phys slot p = c&7
  // sigma = p ^ (row&7) ; row&7 identical for both i (64 % 8 == 0)
  const int r0 = tid >> 3;                  // 0..63
  const int sg = (tid & 7) ^ (r0 & 7);
  const unsigned short* asrc[2];
  const unsigned short* bsrc[2];
#pragma unroll
  for (int i = 0; i < 2; i++) {
    const int r = r0 + i * 64;
    const long ridx = x[(b0 + r) * SEQ + t_idx];
    asrc[i] = embb + ridx * EMBP + sg * 8;
    bsrc[i] = wihb + (long)(n0 + r) * EMBP + sg * 8;
  }

  // wave mapping: 8 waves = 4 wrow (32 M-rows) x 2 wcol (64 N-cols)
  const int wid = tid >> 6;
  const int wrow = wid >> 1, wcol = wid & 1;
  const int l15 = lane & 15, lgrp = lane >> 4;
  const int swz = (l15 & 7) << 4;

  f32x4 acc[2][4];
#pragma unroll
  for (int mt = 0; mt < 2; mt++)
#pragma unroll
    for (int nt = 0; nt < 4; nt++) acc[mt][nt] = (f32x4){0.f, 0.f, 0.f, 0.f};

#define STAGE(KS, BUF)                                                         \
  {                                                                            \
    _Pragma("unroll") for (int i = 0; i < 2; i++) {                            \
      gload_lds16(asrc[i] + (KS) * 64, (char*)Al + (BUF) * 16384 + tid * 16 + i * 8192); \
      gload_lds16(bsrc[i] + (KS) * 64, (char*)Bl + (BUF) * 16384 + tid * 16 + i * 8192); \
    }                                                                          \
  }

#define COMPUTE(BUF)                                                           \
  {                                                                            \
    const char* Ar = (const char*)Al + (BUF) * 16384 + (wrow * 32) * 128;      \
    const char* Br = (const char*)Bl + (BUF) * 16384 + (wcol * 64) * 128;      \
    _Pragma("unroll") for (int kt = 0; kt < 2; kt++) {                         \
      short8 af[2], bf[4];                                                     \
      _Pragma("unroll") for (int mt = 0; mt < 2; mt++)                         \
        af[mt] = *(const short8*)(Ar + (mt * 16 + l15) * 128 + ((kt * 64 + lgrp * 16) ^ swz)); \
      _Pragma("unroll") for (int nt = 0; nt < 4; nt++)                         \
        bf[nt] = *(const short8*)(Br + (nt * 16 + l15) * 128 + ((kt * 64 + lgrp * 16) ^ swz)); \
      _Pragma("unroll") for (int mt = 0; mt < 2; mt++)                         \
        _Pragma("unroll") for (int nt = 0; nt < 4; nt++)                       \
          acc[mt][nt] = __builtin_amdgcn_mfma_f32_16x16x32_bf16(af[mt], bf[nt], acc[mt][nt], 0, 0, 0); \
    }                                                                          \
  }

  STAGE(0, 0);
  __syncthreads();
  STAGE(1, 1); COMPUTE(0); __syncthreads();
  STAGE(2, 0); COMPUTE(1); __syncthreads();
  STAGE(3, 1); COMPUTE(0); __syncthreads();
  STAGE(4, 0); COMPUTE(1); __syncthreads();
  COMPUTE(0);
#undef STAGE
#undef COMPUTE

  const int m_base = tile_m * 128 + wrow * 32;
  const int colg = n0 + wcol * 64 + l15;
  const int rsub = lgrp * 4;
  float bv[4];
#pragma unroll
  for (int nt = 0; nt < 4; nt++) bv[nt] = biasp[colg + nt * 16];
#pragma unroll
  for (int mt = 0; mt < 2; mt++)
#pragma unroll
    for (int nt = 0; nt < 4; nt++)
#pragma unroll
      for (int j = 0; j < 4; j++) {
        const long m = m_base + mt * 16 + rsub + j;
        xg[m * NGATE + colg + nt * 16] = f2bf(acc[mt][nt][j] + bv[nt]);
      }
}

// ---------------- kernel 2: sequential LSTM (R9 champion, verbatim) --------
__global__ __launch_bounds__(512, 2) void k_lstm(
    const unsigned short* __restrict__ xg, const unsigned short* __restrict__ whhp,
    float* __restrict__ hfin) {
  __shared__ __align__(16) unsigned short h_lds[2 * 4 * 128];  // 2KB dbuf, XOR-swizzled
  __shared__ __align__(16) float scratch[8 * 256];             // 8KB: 1KB per wave
  const int tid = threadIdx.x;
  const int lane = tid & 63;
  const int wid = tid >> 6;        // hidden block (16 hids)
  const int b0 = blockIdx.x * ROWS;
  const int l15 = lane & 15;
  const int lgrp = lane >> 4;      // 0..3
  const int hid = wid * 16 + l15;  // updater's hid

  // A-operand: permuted w_hh rows n' = wid*64 + nt*16 + l15, k = kt*32+lgrp*8
  short8 wfr[4][4];
#pragma unroll
  for (int nt = 0; nt < 4; nt++)
#pragma unroll
    for (int kt = 0; kt < 4; kt++)
      wfr[nt][kt] = *(const short8*)(whhp + (long)(wid * 64 + nt * 16 + l15) * HID + kt * 32 + lgrp * 8);

  float c_r = 0.0f, h_r = 0.0f;    // element (row=lgrp, hid)

  ((unsigned*)h_lds)[tid] = 0;     // 512 x 4B = 2KB (both parities)
  __syncthreads();

  // B-frag (h^T): lane l15 -> batch row l15&3 (rows 4-15 dup -> garbage cols)
  const int ar = l15 & 3;
  int rdoff[4];
#pragma unroll
  for (int kt = 0; kt < 4; kt++)
    rdoff[kt] = ar * 256 + ((kt * 64 + lgrp * 16) ^ (ar << 5));
  const int hwoff = lgrp * 256 + ((2 * hid) ^ (lgrp << 5));
  const char* lb = (const char*)h_lds;

  // wave-private scratch: float addr (row r)*64 + ((hidloc*4) ^ (r*4))
  float* sw = scratch + wid * 256;
  int swr[4];                       // write: r=l15 (<4), hidloc = nt*4+lgrp
#pragma unroll
  for (int nt = 0; nt < 4; nt++)
    swr[nt] = l15 * 64 + (((nt * 4 + lgrp) * 4) ^ (l15 * 4));
  const int srd = lgrp * 64 + ((l15 * 4) ^ (lgrp * 4));  // read: r=lgrp, hidloc=l15

  // xg: elem ((t*BATCH + row)*HID + hid)*4 + gate ; this lane: row=lgrp
  const unsigned short* xbase = xg + ((long)(b0 + lgrp) * HID + hid) * 4;
  const long TSTEP = (long)BATCH * HID * 4;
  uint2 xA = *(const uint2*)xbase;
  uint2 xB = *(const uint2*)(xbase + TSTEP);
  const unsigned short* xnext = xbase + 2 * TSTEP;

#define STEP_BODY(XS, RB, WB, T)                                               \
  {                                                                            \
    const float xf0 = blo2f(XS.x), xf1 = bhi2f(XS.x);                          \
    const float xf2 = blo2f(XS.y), xf3 = bhi2f(XS.y);                          \
    if ((T) + 2 < SEQ) XS = *(const uint2*)xnext;                              \
    short8 hf[4];                                                              \
    _Pragma("unroll") for (int kt = 0; kt < 4; kt++)                           \
      hf[kt] = *(const short8*)(lb + (RB) + rdoff[kt]);                        \
    f32x4 acc[4];                                                              \
    _Pragma("unroll") for (int nt = 0; nt < 4; nt++)                           \
      acc[nt] = (f32x4){0.f, 0.f, 0.f, 0.f};                                   \
    _Pragma("unroll") for (int kt = 0; kt < 4; kt++)                           \
      _Pragma("unroll") for (int nt = 0; nt < 4; nt++)                         \
        acc[nt] = __builtin_amdgcn_mfma_f32_16x16x32_bf16(wfr[nt][kt], hf[kt], \
                                                          acc[nt], 0, 0, 0);   \
    if (l15 < 4) {                                                             \
      _Pragma("unroll") for (int nt = 0; nt < 4; nt++)                         \
        *(f32x4*)(sw + swr[nt]) = acc[nt];                                     \
    }                                                                          \
    __builtin_amdgcn_sched_barrier(0);                                         \
    const f32x4 g4 = *(const f32x4*)(sw + srd);                                \
    const float zi = g4[0] + xf0;                                              \
    const float zf = g4[1] + xf1;                                              \
    const float zg = g4[2] + xf2;                                              \
    const float zo = g4[3] + xf3;                                              \
    const float iv = sig2(zi);                                                 \
    const float fv = sig2(zf);                                                 \
    const float gv = 2.0f * sig2(zg) - 1.0f;                                   \
    const float ov = sig2(zo);                                                 \
    c_r = fv * c_r + iv * gv;                                                  \
    const float tc = 2.0f * sig2(c_r * (2.0f * L2E)) - 1.0f;                   \
    h_r = ov * tc;                                                             \
    *(unsigned short*)((char*)h_lds + (WB) + hwoff) = f2bf(h_r);               \
    asm volatile("s_waitcnt lgkmcnt(0)" ::: "memory");                         \
    __builtin_amdgcn_s_barrier();                                              \
    __builtin_amdgcn_sched_barrier(0);                                         \
  }

  for (int t = 0; t < SEQ; t += 2) {
    STEP_BODY(xA, 0, 1024, t);
    xnext += TSTEP;
    STEP_BODY(xB, 1024, 0, t + 1);
    xnext += TSTEP;
  }
#undef STEP_BODY

  hfin[(b0 + lgrp) * HID + hid] = h_r;
}

// ---------------- kernel 3: FC head, one wave per batch row ----------------
__global__ void k_head(const float* __restrict__ hfin,
                       const float* __restrict__ fc1w, const float* __restrict__ fc1b,
                       const float* __restrict__ fc2w, const float* __restrict__ fc2b,
                       float* __restrict__ out) {
  const int tid = threadIdx.x;
  const int lane = tid & 63;
  const int wid = tid >> 6;
  const int row = blockIdx.x * 4 + wid;
  const float* h = hfin + row * HID;
  const float* w = fc1w + lane * HID;
  float acc = 0.0f;
#pragma unroll
  for (int k = 0; k < HID; k += 4) {
    const f32x4 hv = *(const f32x4*)(h + k);
    const f32x4 wv = *(const f32x4*)(w + k);
    acc += hv[0] * wv[0] + hv[1] * wv[1] + hv[2] * wv[2] + hv[3] * wv[3];
  }
  const float h1 = fmaxf(acc + fc1b[lane], 0.0f);
  float v = h1 * fc2w[lane];
#pragma unroll
  for (int off = 32; off > 0; off >>= 1) v += __shfl_down(v, off, 64);
  if (lane == 0) out[row] = sigmf(v + fc2b[0]);
}

// ---------------------------------------------------------------------------
extern "C" void kernel_launch(void* const* d_in, const int* in_sizes, int n_in,
                              void* d_out, int out_size, void* d_ws, size_t ws_size,
                              hipStream_t stream) {
  const int*   x    = (const int*)d_in[0];
  const float* emb  = (const float*)d_in[1];
  const float* w_ih = (const float*)d_in[2];
  const float* w_hh = (const float*)d_in[3];
  const float* b_ih = (const float*)d_in[4];
  const float* b_hh = (const float*)d_in[5];
  const float* fc1w = (const float*)d_in[6];
  const float* fc1b = (const float*)d_in[7];
  const float* fc2w = (const float*)d_in[8];
  const float* fc2b = (const float*)d_in[9];
  float* out = (float*)d_out;
  char* ws = (char*)d_ws;

  unsigned short* embb = (unsigned short*)(ws + 0);            // 32,000,000
  unsigned short* wihb = (unsigned short*)(ws + 32000000);     //    327,680
  unsigned short* whhp = (unsigned short*)(ws + 32327680);     //    131,072 (PERMUTED w_hh)
  float*          biasp= (float*)(ws + 32458752);              //      2,048
  float*          hfinp= (float*)(ws + 32460800);              //    524,288
  unsigned short* xgb  = (unsigned short*)(ws + 32985088);     // 209,715,200

  k_cvt_pad<<<dim3((VOCAB * (EMBP / 8) + 255) / 256), dim3(256), 0, stream>>>(emb, embb, VOCAB, EMB, EMBP, 0, 0);
  k_cvt_pad<<<dim3((NGATE * (EMBP / 8) + 255) / 256), dim3(256), 0, stream>>>(w_ih, wihb, NGATE, EMB, EMBP, 1, 1);
  k_cvt_pad<<<dim3((NGATE * (HID / 8) + 255) / 256), dim3(256), 0, stream>>>(w_hh, whhp, NGATE, HID, HID, 1, 1);
  k_bias<<<dim3(2), dim3(256), 0, stream>>>(b_ih, b_hh, biasp);
  k_xg_gemm<<<dim3(1600 * 4), dim3(512), 0, stream>>>(x, embb, wihb, biasp, xgb);
  k_lstm<<<dim3(BATCH / ROWS), dim3(512), 0, stream>>>(xgb, whhp, hfinp);
  k_head<<<dim3(256), dim3(256), 0, stream>>>(hfinp, fc1w, fc1b, fc2w, fc2b, out);
  (void)in_sizes; (void)n_in; (void)out_size; (void)ws_size;
}